// Round 4
// baseline (731.443 us; speedup 1.0000x reference)
//
#include <hip/hip_runtime.h>
#include <hip/hip_bf16.h>

typedef unsigned short ushort_t;

// Problem constants
#define DMODEL 1024
#define HD     64
#define NHEAD  16
#define BATCH  4
#define TQ     1024
#define SCACHE 3072
#define STOT   4096

#define OUT_ELEMS   (BATCH * TQ * DMODEL)
#define KV_ELEMS    (BATCH * STOT * DMODEL)
#define K_OFF       OUT_ELEMS
#define V_OFF       (OUT_ELEMS + KV_ELEMS)

using frag_ab = __attribute__((ext_vector_type(8))) short;   // 8 bf16
using f32x4   = __attribute__((ext_vector_type(4))) float;
using u16x4   = __attribute__((ext_vector_type(4))) unsigned short;

static __device__ __forceinline__ short f2bf(float f) {
    union { float f; unsigned u; } v; v.f = f;
    unsigned r = (v.u + 0x7FFFu + ((v.u >> 16) & 1u)) >> 16;  // RNE
    return (short)r;
}
static __device__ __forceinline__ float bf2f(ushort_t h) {
    union { unsigned u; float f; } v; v.u = ((unsigned)h) << 16; return v.f;
}

// global->LDS direct staging (16B per lane); compile-safe fallback
static __device__ __forceinline__ void stage16(const void* g, void* l) {
#if __has_builtin(__builtin_amdgcn_global_load_lds)
    __builtin_amdgcn_global_load_lds(
        (const __attribute__((address_space(1))) unsigned int*)g,
        (__attribute__((address_space(3))) unsigned int*)l, 16, 0, 0);
#else
    *(frag_ab*)l = *(const frag_ab*)g;
#endif
}

// ===========================================================================
// ws layout (bytes) for the fast path
// ===========================================================================
#define WS_XHI   0ull
#define WS_XLO   8388608ull
#define WS_WTHI  16777216ull    // [3072][1024] bf16  (q,k,v stacked W^T)
#define WS_WTLO  23068672ull
#define WS_WOHI  29360128ull    // [1024][1024] bf16  (Wo^T)
#define WS_WOLO  31457280ull
#define WS_BIAS  33554432ull    // [3072] f32 (bq | 0 | bv)
#define WS_QBF   33570816ull    // [4][1024][1024] bf16
#define WS_KBF   41959424ull    // [4][4096][1024] bf16
#define WS_VBT   75513856ull    // [4][1024][4096] bf16 (V transposed)
#define WS_AHI   109068288ull   // attention out hi [4][1024][1024] bf16
#define WS_ALO   117456896ull
#define WS_FULL  125845504ull

// ===========================================================================
// cache copy: fp32 k/v outputs (+ optional bf16 K copy)
// ===========================================================================
__global__ void copy_caches(const float4* __restrict__ kc, const float4* __restrict__ vc,
                            float4* __restrict__ ko, float4* __restrict__ vo,
                            u16x4* __restrict__ kbf)
{
    const int per_b = SCACHE * DMODEL / 4;
    const int ob    = STOT * DMODEL / 4;
    const int total = BATCH * per_b;
    for (int i = blockIdx.x * blockDim.x + threadIdx.x; i < total;
         i += gridDim.x * blockDim.x) {
        int b = i / per_b;
        int r = i - b * per_b;
        float4 k4 = kc[i];
        ko[b * ob + r] = k4;
        vo[b * ob + r] = vc[i];
        if (kbf) {
            u16x4 h;
            h[0] = (ushort_t)f2bf(k4.x); h[1] = (ushort_t)f2bf(k4.y);
            h[2] = (ushort_t)f2bf(k4.z); h[3] = (ushort_t)f2bf(k4.w);
            kbf[(size_t)b * ob + r] = h;
        }
    }
}

// ===========================================================================
// x -> hi/lo bf16
// ===========================================================================
__global__ void convert_x(const float4* __restrict__ x,
                          u16x4* __restrict__ hi, u16x4* __restrict__ lo)
{
    const int total = BATCH * TQ * DMODEL / 4;
    for (int i = blockIdx.x * blockDim.x + threadIdx.x; i < total;
         i += gridDim.x * blockDim.x) {
        float4 v = x[i];
        u16x4 h, l;
        h[0] = (ushort_t)f2bf(v.x); h[1] = (ushort_t)f2bf(v.y);
        h[2] = (ushort_t)f2bf(v.z); h[3] = (ushort_t)f2bf(v.w);
        l[0] = (ushort_t)f2bf(v.x - bf2f(h[0]));
        l[1] = (ushort_t)f2bf(v.y - bf2f(h[1]));
        l[2] = (ushort_t)f2bf(v.z - bf2f(h[2]));
        l[3] = (ushort_t)f2bf(v.w - bf2f(h[3]));
        hi[i] = h; lo[i] = l;
    }
}

// ===========================================================================
// W[k][n] -> W^T hi/lo bf16 [n][k], tiled transpose. z selects Wq/Wk/Wv/Wo.
// ===========================================================================
__global__ __launch_bounds__(256) void transconv_w(
    const float* __restrict__ Wq, const float* __restrict__ Wk,
    const float* __restrict__ Wv, const float* __restrict__ Wo,
    ushort_t* __restrict__ WtHi, ushort_t* __restrict__ WtLo,
    ushort_t* __restrict__ WoHi, ushort_t* __restrict__ WoLo)
{
    __shared__ float T[32][33];
    const int z = blockIdx.z;
    const float* src = (z == 0) ? Wq : (z == 1) ? Wk : (z == 2) ? Wv : Wo;
    ushort_t* dhi = (z < 3) ? WtHi + (size_t)z * 1024 * 1024 : WoHi;
    ushort_t* dlo = (z < 3) ? WtLo + (size_t)z * 1024 * 1024 : WoLo;
    const int tx = threadIdx.x & 31, ty = threadIdx.x >> 5;
    const int k0 = blockIdx.y * 32, n0 = blockIdx.x * 32;
    #pragma unroll
    for (int s = 0; s < 4; ++s)
        T[ty + s * 8][tx] = src[(size_t)(k0 + ty + s * 8) * 1024 + n0 + tx];
    __syncthreads();
    #pragma unroll
    for (int s = 0; s < 4; ++s) {
        int n = n0 + ty + s * 8, k = k0 + tx;
        float v = T[tx][ty + s * 8];
        ushort_t h = (ushort_t)f2bf(v);
        ushort_t l = (ushort_t)f2bf(v - bf2f(h));
        dhi[(size_t)n * 1024 + k] = h;
        dlo[(size_t)n * 1024 + k] = l;
    }
}

__global__ void build_bias(const float* __restrict__ bq, const float* __restrict__ bv,
                           float* __restrict__ b3)
{
    int i = blockIdx.x * blockDim.x + threadIdx.x;
    if (i < 3072)
        b3[i] = (i < 1024) ? bq[i] : (i < 2048) ? 0.0f : bv[i - 2048];
}

// ===========================================================================
// vout fp32 [b][s][1024] -> Vbt bf16 [b][1024][4096]
// ===========================================================================
__global__ __launch_bounds__(256) void transpose_v(
    const float* __restrict__ vout, ushort_t* __restrict__ vbt)
{
    __shared__ float T[32][33];
    const int b = blockIdx.z;
    const int s0 = blockIdx.x * 32, d0 = blockIdx.y * 32;
    const int tx = threadIdx.x & 31, ty = threadIdx.x >> 5;
    #pragma unroll
    for (int s = 0; s < 4; ++s)
        T[ty + s * 8][tx] = vout[(size_t)(b * STOT + s0 + ty + s * 8) * 1024 + d0 + tx];
    __syncthreads();
    #pragma unroll
    for (int s = 0; s < 4; ++s) {
        int d = d0 + ty + s * 8, sx = s0 + tx;
        vbt[((size_t)b * 1024 + d) * STOT + sx] = (ushort_t)f2bf(T[tx][ty + s * 8]);
    }
}

// ===========================================================================
// Split-bf16 MFMA GEMM: C[M][N] = A(hi+lo)[M][1024] @ Bt(hi+lo)^T + bias
// Bt stored [n][k]. 2x2 waves, each MI x NI frags of 16x16 (16x16x32 MFMA).
// MODE 0: plain fp32 out. MODE 1: fused QKV routing.
// ===========================================================================
template<int MI, int NI, int MODE>
__global__ __launch_bounds__(256) void gemm_sb(
    const ushort_t* __restrict__ Ahi, const ushort_t* __restrict__ Alo,
    const ushort_t* __restrict__ Bhi, const ushort_t* __restrict__ Blo,
    const float* __restrict__ bias,
    float* __restrict__ C0, float* __restrict__ C1,
    ushort_t* __restrict__ Qbf, ushort_t* __restrict__ Kbf)
{
    constexpr int BM = MI * 32, BN = NI * 32;
    __shared__ ushort_t AhiL[BM][32], AloL[BM][32], BhiL[BN][32], BloL[BN][32];
    const int tid = threadIdx.x;
    const int w = tid >> 6, lane = tid & 63, c = lane & 15, g = lane >> 4;
    const int wm = w >> 1, wn = w & 1;
    const int bm = blockIdx.y * BM, bn = blockIdx.x * BN;

    f32x4 acc[MI][NI] = {};

    for (int k0 = 0; k0 < 1024; k0 += 32) {
        __syncthreads();
        #pragma unroll
        for (int q = 0; q < BM / 64; ++q) {
            int flat = q * 256 + tid;
            int row = flat >> 2, ch = flat & 3;
            size_t go = (size_t)(bm + row) * 1024 + k0 + ch * 8;
            stage16(Ahi + go, &AhiL[0][0] + (size_t)flat * 8);
            stage16(Alo + go, &AloL[0][0] + (size_t)flat * 8);
        }
        #pragma unroll
        for (int q = 0; q < BN / 64; ++q) {
            int flat = q * 256 + tid;
            int row = flat >> 2, ch = flat & 3;
            size_t go = (size_t)(bn + row) * 1024 + k0 + ch * 8;
            stage16(Bhi + go, &BhiL[0][0] + (size_t)flat * 8);
            stage16(Blo + go, &BloL[0][0] + (size_t)flat * 8);
        }
        __syncthreads();

        frag_ab ah[MI], al[MI], bh[NI], bl[NI];
        #pragma unroll
        for (int mi = 0; mi < MI; ++mi) {
            int r = wm * MI * 16 + mi * 16 + c;
            ah[mi] = *(const frag_ab*)&AhiL[r][g * 8];
            al[mi] = *(const frag_ab*)&AloL[r][g * 8];
        }
        #pragma unroll
        for (int ni = 0; ni < NI; ++ni) {
            int r = wn * NI * 16 + ni * 16 + c;
            bh[ni] = *(const frag_ab*)&BhiL[r][g * 8];
            bl[ni] = *(const frag_ab*)&BloL[r][g * 8];
        }
        #pragma unroll
        for (int mi = 0; mi < MI; ++mi)
            #pragma unroll
            for (int ni = 0; ni < NI; ++ni) {
                acc[mi][ni] = __builtin_amdgcn_mfma_f32_16x16x32_bf16(ah[mi], bh[ni], acc[mi][ni], 0, 0, 0);
                acc[mi][ni] = __builtin_amdgcn_mfma_f32_16x16x32_bf16(ah[mi], bl[ni], acc[mi][ni], 0, 0, 0);
                acc[mi][ni] = __builtin_amdgcn_mfma_f32_16x16x32_bf16(al[mi], bh[ni], acc[mi][ni], 0, 0, 0);
            }
    }

    const int seg = (MODE == 0) ? 0 : (bn >> 10);
    #pragma unroll
    for (int mi = 0; mi < MI; ++mi) {
        #pragma unroll
        for (int ni = 0; ni < NI; ++ni) {
            const int ncol = bn + wn * NI * 16 + ni * 16 + c;
            const float bv = bias[ncol];
            #pragma unroll
            for (int i = 0; i < 4; ++i) {
                const int grow = bm + wm * MI * 16 + mi * 16 + g * 4 + i;
                float val = acc[mi][ni][i] + bv;
                if (MODE == 0) {
                    C0[(size_t)grow * 1024 + ncol] = val;
                } else if (seg == 0) {
                    Qbf[(size_t)grow * 1024 + ncol] = (ushort_t)f2bf(val);
                } else {
                    const int n2 = ncol & 1023;
                    const size_t drow = (size_t)(grow >> 10) * STOT + SCACHE + (grow & 1023);
                    if (seg == 1) {
                        C0[drow * 1024 + n2] = val;
                        Kbf[drow * 1024 + n2] = (ushort_t)f2bf(val);
                    } else {
                        C1[drow * 1024 + n2] = val;
                    }
                }
            }
        }
    }
}

// ===========================================================================
// Flash attention, bf16 operands, LDS-staged K/V shared by 4 waves per block.
// Block: (b, h, 64 queries); wave w handles queries q0..q0+15.
// Mask: key j masked iff j < TQ && j > t (faithful reference quirk).
// Defer-max (T13): skip corr/rescale when no row's max grew this tile.
// ===========================================================================
__global__ __launch_bounds__(256) void attn_bf16(
    const ushort_t* __restrict__ Qbf,   // [4][1024][1024]
    const ushort_t* __restrict__ Kbf,   // [4][4096][1024]
    const ushort_t* __restrict__ Vbt,   // [4][1024][4096]
    ushort_t* __restrict__ OHi, ushort_t* __restrict__ OLo)
{
    __shared__ ushort_t Klds[32][72];       // [key][d]
    __shared__ ushort_t Vlds[64][40];       // [d][key]
    __shared__ ushort_t Plds[4][16][40];    // per-wave P tile
    const int tid = threadIdx.x;
    const int w = tid >> 6, lane = tid & 63, c = lane & 15, g = lane >> 4;
    const int b = blockIdx.z, h = blockIdx.y;
    const int q0 = blockIdx.x * 64 + w * 16;

    frag_ab qf[2];
    {
        const ushort_t* qp = Qbf + ((size_t)(b * TQ + q0 + c)) * 1024 + h * HD + g * 8;
        qf[0] = *(const frag_ab*)qp;
        qf[1] = *(const frag_ab*)(qp + 32);
    }

    f32x4 acc[4] = {};
    float m_run[4], l_run[4];
    #pragma unroll
    for (int i = 0; i < 4; ++i) { m_run[i] = -1e30f; l_run[i] = 0.0f; }

    const ushort_t* Kh = Kbf + (size_t)b * STOT * 1024 + h * HD;
    const ushort_t* Vh = Vbt + ((size_t)b * 1024 + h * HD) * STOT;
    const int krow = tid >> 3, kch = tid & 7;
    const int vrow = tid >> 2, vch = tid & 3;
    const int tq0 = q0 + g * 4;                       // first of this thread's 4 q rows

    frag_ab gk = *(const frag_ab*)(Kh + (size_t)krow * 1024 + kch * 8);
    frag_ab gv = *(const frag_ab*)(Vh + (size_t)vrow * STOT + vch * 8);

    for (int ks = 0; ks < STOT; ks += 32) {
        __syncthreads();
        *(frag_ab*)&Klds[krow][kch * 8] = gk;
        *(frag_ab*)&Vlds[vrow][vch * 8] = gv;
        __syncthreads();
        if (ks + 32 < STOT) {
            gk = *(const frag_ab*)(Kh + (size_t)(ks + 32 + krow) * 1024 + kch * 8);
            gv = *(const frag_ab*)(Vh + (size_t)vrow * STOT + ks + 32 + vch * 8);
        }

        // QK^T
        f32x4 s[2];
        #pragma unroll
        for (int sub = 0; sub < 2; ++sub) {
            f32x4 z = {0.f, 0.f, 0.f, 0.f};
            #pragma unroll
            for (int half = 0; half < 2; ++half) {
                frag_ab kf = *(const frag_ab*)&Klds[sub * 16 + c][half * 32 + g * 8];
                z = __builtin_amdgcn_mfma_f32_16x16x32_bf16(qf[half], kf, z, 0, 0, 0);
            }
            s[sub] = z;
        }

        // scale + mask + row-max (rows tq0..tq0+3, cols over 16 lanes)
        const int k0i = ks + c, k1i = ks + 16 + c;
        const bool m0c = (k0i < TQ), m1c = (k1i < TQ);
        float mt[4];
        #pragma unroll
        for (int i = 0; i < 4; ++i) {
            const int tq = tq0 + i;
            float s0 = s[0][i] * 0.125f, s1 = s[1][i] * 0.125f;
            if (m0c && k0i > tq) s0 = -1e30f;
            if (m1c && k1i > tq) s1 = -1e30f;
            s[0][i] = s0; s[1][i] = s1;
            float v = fmaxf(s0, s1);
            v = fmaxf(v, __shfl_xor(v, 1));
            v = fmaxf(v, __shfl_xor(v, 2));
            v = fmaxf(v, __shfl_xor(v, 4));
            v = fmaxf(v, __shfl_xor(v, 8));
            mt[i] = v;
        }

        // defer-max: only rescale when some row's max actually grew
        bool grew = (mt[0] > m_run[0]) | (mt[1] > m_run[1]) |
                    (mt[2] > m_run[2]) | (mt[3] > m_run[3]);
        if (__any(grew)) {
            #pragma unroll
            for (int i = 0; i < 4; ++i) {
                float mn = fmaxf(m_run[i], mt[i]);
                float corr = __expf(m_run[i] - mn);
                m_run[i] = mn;
                l_run[i] *= corr;
                #pragma unroll
                for (int f = 0; f < 4; ++f) acc[f][i] *= corr;
            }
        }

        // exp + row-sum + P
        float p0[4], p1[4];
        #pragma unroll
        for (int i = 0; i < 4; ++i) {
            p0[i] = __expf(s[0][i] - m_run[i]);
            p1[i] = __expf(s[1][i] - m_run[i]);
            float rs = p0[i] + p1[i];
            rs += __shfl_xor(rs, 1);
            rs += __shfl_xor(rs, 2);
            rs += __shfl_xor(rs, 4);
            rs += __shfl_xor(rs, 8);
            l_run[i] += rs;
        }

        // P -> LDS (D-layout), reload as A-frag
        ushort_t* pl = &Plds[w][0][0];
        #pragma unroll
        for (int i = 0; i < 4; ++i) {
            int row = g * 4 + i;
            pl[row * 40 + c]      = (ushort_t)f2bf(p0[i]);
            pl[row * 40 + 16 + c] = (ushort_t)f2bf(p1[i]);
        }
        frag_ab pa = *(const frag_ab*)(pl + c * 40 + g * 8);

        // PV: V frags contiguous from transposed LDS
        #pragma unroll
        for (int f = 0; f < 4; ++f) {
            frag_ab vf = *(const frag_ab*)&Vlds[f * 16 + c][g * 8];
            acc[f] = __builtin_amdgcn_mfma_f32_16x16x32_bf16(pa, vf, acc[f], 0, 0, 0);
        }
    }

    // epilogue: normalize, emit hi/lo bf16
    #pragma unroll
    for (int f = 0; f < 4; ++f)
        #pragma unroll
        for (int i = 0; i < 4; ++i) {
            float o = acc[f][i] / l_run[i];
            ushort_t hi = (ushort_t)f2bf(o);
            ushort_t lo = (ushort_t)f2bf(o - bf2f(hi));
            size_t idx = ((size_t)(b * TQ + q0 + g * 4 + i)) * 1024 + h * HD + f * 16 + c;
            OHi[idx] = hi;
            OLo[idx] = lo;
        }
}

// ===========================================================================
// ===== Fallback path (round-1): fp32 GEMM + fp32-operand attention =========
// ===========================================================================
__global__ __launch_bounds__(256) void gemm_f32(
    const float* __restrict__ X, const float* __restrict__ Wm,
    const float* __restrict__ bias, float* __restrict__ Cb,
    int OS, int OFF)
{
    __shared__ float As[8][128];
    __shared__ float Bs[8][132];
    const int tid = threadIdx.x;
    const int tx = tid & 15, ty = tid >> 4;
    const int bm = blockIdx.y * 128, bn = blockIdx.x * 128;
    const int arow = tid >> 1, acol = (tid & 1) * 4;
    const int brow = tid >> 5, bcol = (tid & 31) * 4;

    float acc[8][8] = {};
    const float* Aptr = X + (size_t)(bm + arow) * DMODEL + acol;
    const float* Bptr = Wm + (size_t)brow * DMODEL + bn + bcol;

    for (int k0 = 0; k0 < DMODEL; k0 += 8) {
        float4 av = *(const float4*)(Aptr + k0);
        float4 bv = *(const float4*)(Bptr + (size_t)k0 * DMODEL);
        __syncthreads();
        As[acol + 0][arow] = av.x;
        As[acol + 1][arow] = av.y;
        As[acol + 2][arow] = av.z;
        As[acol + 3][arow] = av.w;
        *(float4*)&Bs[brow][bcol] = bv;
        __syncthreads();
        #pragma unroll
        for (int kk = 0; kk < 8; ++kk) {
            float a[8], bb[8];
            *(float4*)&a[0]  = *(const float4*)&As[kk][ty * 8];
            *(float4*)&a[4]  = *(const float4*)&As[kk][ty * 8 + 4];
            *(float4*)&bb[0] = *(const float4*)&Bs[kk][tx * 8];
            *(float4*)&bb[4] = *(const float4*)&Bs[kk][tx * 8 + 4];
            #pragma unroll
            for (int i = 0; i < 8; ++i)
                #pragma unroll
                for (int j = 0; j < 8; ++j)
                    acc[i][j] += a[i] * bb[j];
        }
    }

    float bv8[8];
    #pragma unroll
    for (int j = 0; j < 8; ++j) bv8[j] = bias ? bias[bn + tx * 8 + j] : 0.0f;

    #pragma unroll
    for (int i = 0; i < 8; ++i) {
        int r = bm + ty * 8 + i;
        int dstrow = (r >> 10) * OS + OFF + (r & 1023);
        float* cp = Cb + (size_t)dstrow * DMODEL + bn + tx * 8;
        float4 c0 = { acc[i][0] + bv8[0], acc[i][1] + bv8[1],
                      acc[i][2] + bv8[2], acc[i][3] + bv8[3] };
        float4 c1 = { acc[i][4] + bv8[4], acc[i][5] + bv8[5],
                      acc[i][6] + bv8[6], acc[i][7] + bv8[7] };
        *(float4*)cp       = c0;
        *(float4*)(cp + 4) = c1;
    }
}

__global__ __launch_bounds__(256) void attn_f32(
    const float* __restrict__ Qb, const float* __restrict__ Kb,
    const float* __restrict__ Vb, float* __restrict__ Ob)
{
    __shared__ __align__(16) ushort_t Plds[4][16][40];
    const int warp = threadIdx.x >> 6;
    const int lane = threadIdx.x & 63;
    const int c = lane & 15, g = lane >> 4;
    const int W = blockIdx.x * 4 + warp;
    const int qt = W & 63, h = (W >> 6) & 15, b = W >> 10;
    const int q0 = qt * 16;

    frag_ab qf[2];
    {
        const float* qrow = Qb + (size_t)(b * TQ + q0 + c) * DMODEL + h * HD;
        #pragma unroll
        for (int half = 0; half < 2; ++half) {
            const float* p = qrow + half * 32 + g * 8;
            float4 x0 = *(const float4*)p;
            float4 x1 = *(const float4*)(p + 4);
            qf[half][0] = f2bf(x0.x * 0.125f); qf[half][1] = f2bf(x0.y * 0.125f);
            qf[half][2] = f2bf(x0.z * 0.125f); qf[half][3] = f2bf(x0.w * 0.125f);
            qf[half][4] = f2bf(x1.x * 0.125f); qf[half][5] = f2bf(x1.y * 0.125f);
            qf[half][6] = f2bf(x1.z * 0.125f); qf[half][7] = f2bf(x1.w * 0.125f);
        }
    }

    f32x4 acc[4] = {};
    float m_run[4], l_run[4];
    #pragma unroll
    for (int i = 0; i < 4; ++i) { m_run[i] = -1e30f; l_run[i] = 0.0f; }

    const float* Kh = Kb + (size_t)b * STOT * DMODEL + h * HD;
    const float* Vh = Vb + (size_t)b * STOT * DMODEL + h * HD;
    ushort_t* pl = &Plds[warp][0][0];

    for (int ks = 0; ks < STOT; ks += 32) {
        f32x4 s[2];
        #pragma unroll
        for (int sub = 0; sub < 2; ++sub) {
            f32x4 z = {0.f, 0.f, 0.f, 0.f};
            #pragma unroll
            for (int half = 0; half < 2; ++half) {
                const float* kp = Kh + (size_t)(ks + sub * 16 + c) * DMODEL + half * 32 + g * 8;
                float4 x0 = *(const float4*)kp;
                float4 x1 = *(const float4*)(kp + 4);
                frag_ab kf;
                kf[0] = f2bf(x0.x); kf[1] = f2bf(x0.y);
                kf[2] = f2bf(x0.z); kf[3] = f2bf(x0.w);
                kf[4] = f2bf(x1.x); kf[5] = f2bf(x1.y);
                kf[6] = f2bf(x1.z); kf[7] = f2bf(x1.w);
                z = __builtin_amdgcn_mfma_f32_16x16x32_bf16(qf[half], kf, z, 0, 0, 0);
            }
            s[sub] = z;
        }
        float mt[4];
        #pragma unroll
        for (int i = 0; i < 4; ++i) {
            const int tq = q0 + g * 4 + i;
            #pragma unroll
            for (int sub = 0; sub < 2; ++sub) {
                int kidx = ks + sub * 16 + c;
                if (kidx < TQ && kidx > tq) s[sub][i] = -1e30f;
            }
            float v = fmaxf(s[0][i], s[1][i]);
            v = fmaxf(v, __shfl_xor(v, 1));
            v = fmaxf(v, __shfl_xor(v, 2));
            v = fmaxf(v, __shfl_xor(v, 4));
            v = fmaxf(v, __shfl_xor(v, 8));
            mt[i] = v;
        }
        float p0[4], p1[4];
        #pragma unroll
        for (int i = 0; i < 4; ++i) {
            float mn = fmaxf(m_run[i], mt[i]);
            float corr = __expf(m_run[i] - mn);
            m_run[i] = mn;
            l_run[i] *= corr;
            #pragma unroll
            for (int f = 0; f < 4; ++f) acc[f][i] *= corr;
            p0[i] = __expf(s[0][i] - mn);
            p1[i] = __expf(s[1][i] - mn);
            float rs = p0[i] + p1[i];
            rs += __shfl_xor(rs, 1);
            rs += __shfl_xor(rs, 2);
            rs += __shfl_xor(rs, 4);
            rs += __shfl_xor(rs, 8);
            l_run[i] += rs;
        }
        #pragma unroll
        for (int i = 0; i < 4; ++i) {
            int row = g * 4 + i;
            pl[row * 40 + c]      = (ushort_t)f2bf(p0[i]);
            pl[row * 40 + 16 + c] = (ushort_t)f2bf(p1[i]);
        }
        frag_ab pa = *(const frag_ab*)(pl + c * 40 + g * 8);
        #pragma unroll
        for (int f = 0; f < 4; ++f) {
            const float* vp = Vh + (size_t)(ks + g * 8) * DMODEL + f * 16 + c;
            frag_ab vf;
            #pragma unroll
            for (int j = 0; j < 8; ++j) vf[j] = f2bf(vp[(size_t)j * DMODEL]);
            acc[f] = __builtin_amdgcn_mfma_f32_16x16x32_bf16(pa, vf, acc[f], 0, 0, 0);
        }
    }

    float* orow = Ob + (size_t)(b * TQ + q0) * DMODEL + h * HD;
    #pragma unroll
    for (int f = 0; f < 4; ++f)
        #pragma unroll
        for (int i = 0; i < 4; ++i)
            orow[(size_t)(g * 4 + i) * DMODEL + f * 16 + c] = acc[f][i] / l_run[i];
}

// ===========================================================================
extern "C" void kernel_launch(void* const* d_in, const int* in_sizes, int n_in,
                              void* d_out, int out_size, void* d_ws, size_t ws_size,
                              hipStream_t stream) {
    const float* x  = (const float*)d_in[0];
    const float* kc = (const float*)d_in[1];
    const float* vc = (const float*)d_in[2];
    const float* Wq = (const float*)d_in[3];
    const float* bq = (const float*)d_in[4];
    const float* Wk = (const float*)d_in[5];
    const float* Wv = (const float*)d_in[6];
    const float* bv = (const float*)d_in[7];
    const float* Wo = (const float*)d_in[8];
    const float* bo = (const float*)d_in[9];

    float* out  = (float*)d_out;
    float* kout = out + K_OFF;
    float* vout = out + V_OFF;

    if (ws_size >= WS_FULL) {
        uint8_t* W8 = (uint8_t*)d_ws;
        ushort_t* XHI  = (ushort_t*)(W8 + WS_XHI);
        ushort_t* XLO  = (ushort_t*)(W8 + WS_XLO);
        ushort_t* WTHI = (ushort_t*)(W8 + WS_WTHI);
        ushort_t* WTLO = (ushort_t*)(W8 + WS_WTLO);
        ushort_t* WOHI = (ushort_t*)(W8 + WS_WOHI);
        ushort_t* WOLO = (ushort_t*)(W8 + WS_WOLO);
        float*    BIAS = (float*)   (W8 + WS_BIAS);
        ushort_t* QBF  = (ushort_t*)(W8 + WS_QBF);
        ushort_t* KBF  = (ushort_t*)(W8 + WS_KBF);
        ushort_t* VBT  = (ushort_t*)(W8 + WS_VBT);
        ushort_t* AHI  = (ushort_t*)(W8 + WS_AHI);
        ushort_t* ALO  = (ushort_t*)(W8 + WS_ALO);

        copy_caches<<<2048, 256, 0, stream>>>((const float4*)kc, (const float4*)vc,
                                              (float4*)kout, (float4*)vout, (u16x4*)KBF);
        convert_x<<<2048, 256, 0, stream>>>((const float4*)x, (u16x4*)XHI, (u16x4*)XLO);
        transconv_w<<<dim3(32, 32, 4), 256, 0, stream>>>(Wq, Wk, Wv, Wo, WTHI, WTLO, WOHI, WOLO);
        build_bias<<<12, 256, 0, stream>>>(bq, bv, BIAS);
        gemm_sb<4, 4, 1><<<dim3(24, 32), 256, 0, stream>>>(XHI, XLO, WTHI, WTLO, BIAS,
                                                           kout, vout, QBF, KBF);
        transpose_v<<<dim3(128, 32, 4), 256, 0, stream>>>(vout, VBT);
        attn_bf16<<<dim3(16, 16, 4), 256, 0, stream>>>(QBF, KBF, VBT, AHI, ALO);
        gemm_sb<4, 2, 0><<<dim3(16, 32), 256, 0, stream>>>(AHI, ALO, WOHI, WOLO, bo,
                                                           out, nullptr, nullptr, nullptr);
    } else {
        // Fallback (needs only 16 MB ws): fp32 projections + fp32-operand attention
        float* qbuf = out;               // staged in out region, overwritten last
        float* attn = (float*)d_ws;

        copy_caches<<<2048, 256, 0, stream>>>((const float4*)kc, (const float4*)vc,
                                              (float4*)kout, (float4*)vout, nullptr);
        dim3 gg(8, 32);
        gemm_f32<<<gg, 256, 0, stream>>>(x, Wk, nullptr, kout, STOT, SCACHE);
        gemm_f32<<<gg, 256, 0, stream>>>(x, Wv, bv,      vout, STOT, SCACHE);
        gemm_f32<<<gg, 256, 0, stream>>>(x, Wq, bq,      qbuf, TQ,   0);
        attn_f32<<<1024, 256, 0, stream>>>(qbuf, kout, vout, attn);
        gemm_f32<<<gg, 256, 0, stream>>>(attn, Wo, bo, out, TQ, 0);
    }
}